// Round 5
// baseline (1212.319 us; speedup 1.0000x reference)
//
#include <hip/hip_runtime.h>
#include <hip/hip_bf16.h>
#include <hip/hip_fp16.h>
#include <math.h>

using bf16 = __hip_bfloat16;
typedef __attribute__((ext_vector_type(8))) short s8v;   // 8 x bf16 raw (4 VGPRs)
typedef __attribute__((ext_vector_type(4))) float f32x4;

#define B_  4
#define S_  2048
#define D_  1024
#define E_  1536
#define M_  (B_*S_)     // 8192 tokens
#define BE_ (B_*E_)     // 6144 sequences
#define NCH 16          // scan chunks
#define CHS (S_/NCH)    // 128 steps per chunk

__device__ __forceinline__ float b2f(bf16 h) { return __bfloat162float(h); }
__device__ __forceinline__ bf16  f2b(float f) { return __float2bfloat16(f); }

struct __align__(8)  bh4 { bf16 h[4]; };

// ---------------- depthwise causal conv (K=4), fp32 in -> bf16 out ----------------
__global__ __launch_bounds__(256) void dwconv_k(const float* __restrict__ x,
                                                const float* __restrict__ w,
                                                const float* __restrict__ bias,
                                                bf16* __restrict__ out)
{
  int m = blockIdx.x;          // b*S + s
  int s = m & (S_ - 1);
  int d = threadIdx.x * 4;
  float wf[4][4];
#pragma unroll
  for (int i = 0; i < 4; ++i) {
    float4 wr = *(const float4*)(w + (d + i) * 4);
    wf[i][0] = wr.x; wf[i][1] = wr.y; wf[i][2] = wr.z; wf[i][3] = wr.w;
  }
  float4 bb = *(const float4*)(bias + d);
  float acc[4] = {bb.x, bb.y, bb.z, bb.w};
#pragma unroll
  for (int k = 0; k < 4; ++k) {
    if (s - 3 + k >= 0) {
      float4 xv = *(const float4*)(x + (size_t)(m - 3 + k) * D_ + d);
      acc[0] += xv.x * wf[0][k];
      acc[1] += xv.y * wf[1][k];
      acc[2] += xv.z * wf[2][k];
      acc[3] += xv.w * wf[3][k];
    }
  }
  bh4 ov;
#pragma unroll
  for (int i = 0; i < 4; ++i) ov.h[i] = f2b(acc[i]);
  *(bh4*)(out + (size_t)m * D_ + d) = ov;
}

// ---------------- GEMM: C(M,N) = A(M,K) * B^T(N,K) ----------------
// A: bf16, row stride K.  B: fp32 weights (row stride ldb), converted to bf16
// during LDS staging. 128x128 tile, BK=64, 4 waves 64x64, 16x16x32 MFMA.
// EPI: 0 outH=bf16(v+bias+resid) | 1 outP=fp16 sigmoid | 2 outH=bf16 sigmoid
//      3 RMW outH=bf16(gh(v)*outH) | 4 outH=bf16(v+resid) | 5 outH=bf16 gelu(v+bias)
//      7 outF=v+bias | 8 outF+=v | 9 outF2=v+outF  (fp32 final store)
template<int EPI>
__global__ __launch_bounds__(256) void gemm_bt(const bf16* __restrict__ A,
                                               const float* __restrict__ Bw, int ldb,
                                               const float* __restrict__ bias,
                                               const float* __restrict__ resid,
                                               bf16* outH, __half* outP,
                                               float* outF, float* outF2,
                                               int M, int N, int K)
{
  __shared__ __align__(16) bf16 lsA[128 * 64];
  __shared__ __align__(16) bf16 lsB[128 * 64];
  const int tid  = threadIdx.x;
  const int lane = tid & 63;
  const int wave = tid >> 6;
  const int m0 = blockIdx.y * 128, n0 = blockIdx.x * 128;
  const int wm = (wave >> 1) * 64, wn = (wave & 1) * 64;
  const int r = lane & 15, q = lane >> 4;
  f32x4 acc[4][4] = {};

  for (int k0 = 0; k0 < K; k0 += 64) {
    int4 ra[4]; float4 rbf[8];
#pragma unroll
    for (int i = 0; i < 4; ++i) {
      int c = i * 256 + tid;          // 16B chunk, 0..1023: row=c>>3, 8 bf16 each
      ra[i] = *(const int4*)(A + (size_t)(m0 + (c >> 3)) * K + k0 + (c & 7) * 8);
    }
#pragma unroll
    for (int i = 0; i < 8; ++i) {
      int c2 = i * 256 + tid;         // 16B fp32 chunk, 0..2047: row=c2>>4, 4 floats
      rbf[i] = *(const float4*)(Bw + (size_t)(n0 + (c2 >> 4)) * ldb + k0 + (c2 & 15) * 4);
    }
    __syncthreads();                  // prev iteration's LDS reads complete
#pragma unroll
    for (int i = 0; i < 4; ++i) {
      int c = i * 256 + tid;
      *(int4*)((char*)lsA + c * 16) = ra[i];
    }
#pragma unroll
    for (int i = 0; i < 8; ++i) {
      int c2 = i * 256 + tid;
      bh4 o;
      o.h[0] = f2b(rbf[i].x); o.h[1] = f2b(rbf[i].y);
      o.h[2] = f2b(rbf[i].z); o.h[3] = f2b(rbf[i].w);
      *(bh4*)(lsB + (c2 >> 4) * 64 + (c2 & 15) * 4) = o;
    }
    __syncthreads();
#pragma unroll
    for (int kk = 0; kk < 64; kk += 32) {
      s8v af[4], bfr[4];
#pragma unroll
      for (int t = 0; t < 4; ++t) {
        af[t]  = *(const s8v*)(lsA + (wm + t * 16 + r) * 64 + kk + q * 8);
        bfr[t] = *(const s8v*)(lsB + (wn + t * 16 + r) * 64 + kk + q * 8);
      }
#pragma unroll
      for (int mi = 0; mi < 4; ++mi)
#pragma unroll
        for (int ni = 0; ni < 4; ++ni)
          acc[mi][ni] = __builtin_amdgcn_mfma_f32_16x16x32_bf16(af[mi], bfr[ni], acc[mi][ni], 0, 0, 0);
    }
  }

#pragma unroll
  for (int mi = 0; mi < 4; ++mi) {
#pragma unroll
    for (int j = 0; j < 4; ++j) {
      int row = m0 + wm + mi * 16 + q * 4 + j;
#pragma unroll
      for (int ni = 0; ni < 4; ++ni) {
        int col = n0 + wn + ni * 16 + r;
        size_t idx = (size_t)row * N + col;
        float v = acc[mi][ni][j];
        if constexpr (EPI == 0) {
          outH[idx] = f2b(v + bias[col] + resid[idx]);
        } else if constexpr (EPI == 1) {
          outP[idx] = __float2half(1.f / (1.f + expf(-v)));
        } else if constexpr (EPI == 2) {
          outH[idx] = f2b(1.f / (1.f + expf(-v)));
        } else if constexpr (EPI == 3) {
          float gh = (v >= 0.f) ? (v + 0.5f) : (1.f / (1.f + expf(-v)));
          outH[idx] = f2b(gh * b2f(outH[idx]));
        } else if constexpr (EPI == 4) {
          outH[idx] = f2b(v + resid[idx]);
        } else if constexpr (EPI == 5) {
          float u = v + bias[col];
          outH[idx] = f2b(0.5f * u * (1.f + erff(u * 0.70710678118f)));
        } else if constexpr (EPI == 7) {
          outF[idx] = v + bias[col];
        } else if constexpr (EPI == 8) {
          outF[idx] += v;
        } else {
          outF2[idx] = v + outF[idx];   // fp32 final store to d_out
        }
      }
    }
  }
}

// ---------------- LayerNorm over D=1024, bf16 in -> bf16 out, fp32 params ----------------
__global__ __launch_bounds__(256) void ln_k(const bf16* __restrict__ y,
                                            const float* __restrict__ g,
                                            const float* __restrict__ b,
                                            bf16* __restrict__ out)
{
  __shared__ float sm[8];
  int row = blockIdx.x;
  bh4 v4 = ((const bh4*)(y + (size_t)row * D_))[threadIdx.x];
  float v0 = b2f(v4.h[0]), v1 = b2f(v4.h[1]), v2 = b2f(v4.h[2]), v3 = b2f(v4.h[3]);
  float s = v0 + v1 + v2 + v3;
#pragma unroll
  for (int o = 32; o; o >>= 1) s += __shfl_down(s, o);
  int lane = threadIdx.x & 63, w = threadIdx.x >> 6;
  if (lane == 0) sm[w] = s;
  __syncthreads();
  float mu = (sm[0] + sm[1] + sm[2] + sm[3]) * (1.f / D_);
  float d0 = v0 - mu, d1 = v1 - mu, d2 = v2 - mu, d3 = v3 - mu;
  float qq = d0 * d0 + d1 * d1 + d2 * d2 + d3 * d3;
#pragma unroll
  for (int o = 32; o; o >>= 1) qq += __shfl_down(qq, o);
  if (lane == 0) sm[4 + w] = qq;
  __syncthreads();
  float var = (sm[4] + sm[5] + sm[6] + sm[7]) * (1.f / D_);
  float inv = rsqrtf(var + 1e-5f);
  int c = threadIdx.x * 4;
  float4 gv = *(const float4*)(g + c);
  float4 bv = *(const float4*)(b + c);
  bh4 ov;
  ov.h[0] = f2b(d0 * inv * gv.x + bv.x);
  ov.h[1] = f2b(d1 * inv * gv.y + bv.y);
  ov.h[2] = f2b(d2 * inv * gv.z + bv.z);
  ov.h[3] = f2b(d3 * inv * gv.w + bv.w);
  *(bh4*)(out + (size_t)row * D_ + c) = ov;
}

// ---------------- chunked linear-recurrence scan: h' = f*h + g ----------------
__global__ __launch_bounds__(256) void scanA_k(const __half* __restrict__ f,
                                               const bf16* __restrict__ g,
                                               float* __restrict__ Fc, float* __restrict__ Gc)
{
  int gth = blockIdx.x * 256 + threadIdx.x;   // = c*BE_ + be
  int c = gth / BE_, be = gth % BE_;
  int b = be / E_,  e = be % E_;
  size_t idx = (size_t)b * S_ * E_ + (size_t)c * CHS * E_ + e;
  float F = 1.f, G = 0.f;
  for (int sl = 0; sl < CHS; ++sl, idx += E_) {
    float fv = __half2float(f[idx]);
    float gv = b2f(g[idx]);
    F *= fv;
    G = fv * G + gv;
  }
  Fc[gth] = F; Gc[gth] = G;
}

__global__ __launch_bounds__(256) void scanB_k(const float* __restrict__ Fc,
                                               const float* __restrict__ Gc,
                                               float* __restrict__ hst)
{
  int be = blockIdx.x * 256 + threadIdx.x;   // 0..6143
  float h = 0.5f;                            // h_0
#pragma unroll
  for (int c = 0; c < NCH; ++c) {
    hst[c * BE_ + be] = h;
    h = Fc[c * BE_ + be] * h + Gc[c * BE_ + be];
  }
}

// writes h IN PLACE over g (each element read before written by the same thread)
__global__ __launch_bounds__(256) void scanC_k(const __half* __restrict__ f,
                                               bf16* g,
                                               const float* __restrict__ hst)
{
  int gth = blockIdx.x * 256 + threadIdx.x;
  int c = gth / BE_, be = gth % BE_;
  int b = be / E_,  e = be % E_;
  size_t idx = (size_t)b * S_ * E_ + (size_t)c * CHS * E_ + e;
  float h = hst[gth];
  for (int sl = 0; sl < CHS; ++sl, idx += E_) {
    float fv = __half2float(f[idx]);
    float gv = b2f(g[idx]);
    h = fv * h + gv;
    g[idx] = f2b(h);
  }
}

extern "C" void kernel_launch(void* const* d_in, const int* in_sizes, int n_in,
                              void* d_out, int out_size, void* d_ws, size_t ws_size,
                              hipStream_t stream)
{
  (void)in_sizes; (void)n_in; (void)out_size; (void)ws_size;
  const float* x      = (const float*)d_in[0];
  const float* cdw_w  = (const float*)d_in[1];
  const float* cdw_b  = (const float*)d_in[2];
  const float* cpw_w  = (const float*)d_in[3];
  const float* cpw_b  = (const float*)d_in[4];
  const float* ln1_g  = (const float*)d_in[5];
  const float* ln1_b  = (const float*)d_in[6];
  const float* w_f    = (const float*)d_in[7];
  const float* w_i    = (const float*)d_in[8];
  const float* w_h    = (const float*)d_in[9];
  const float* w_down = (const float*)d_in[10];
  const float* ln2_g  = (const float*)d_in[11];
  const float* ln2_b  = (const float*)d_in[12];
  const float* mlp_w1 = (const float*)d_in[13];
  const float* mlp_b1 = (const float*)d_in[14];
  const float* mlp_w2 = (const float*)d_in[15];
  const float* mlp_b2 = (const float*)d_in[16];

  // 64 MiB workspace. Kernel order: k1 dwconv, k2 gemm0(pw), k3 ln1, k4 f,
  // k5 i, k6 g(rmw), k7 scanA, k8 scanB, k8c scanC(h in-place over g),
  // k9 gemm4(down), k10 ln2, k11 4x(gemm5-chunk -> gemm6-chunk, fp32 accum),
  // last chunk streams fp32 into d_out.
  //  [0,16M)   dw_buf(k1..k2) -> xln(k3..k6; k10..k11); Fc/Gc/hst(k7..k8c) in [0,1.2M)
  //  [16,32M)  yb1(k2..k3) -> [16,40M) fvals fp16(k4..k8c) -> yb2(k9..k10) -> hmid_c(k11)
  //  [40,64M)  gvals bf16(k5..k8c) -> hvals in place (k8c..k9)
  //  [32,64M)  accum fp32 (k11 only; fvals/gvals dead)
  char* ws = (char*)d_ws;
  bf16*   dw_buf = (bf16*) (ws + 0);
  bf16*   xln    = (bf16*) (ws + 0);
  float*  Fc     = (float*)(ws + 0);
  float*  Gc     = (float*)(ws + 393216);
  float*  hst    = (float*)(ws + 786432);
  bf16*   yb     = (bf16*) (ws + 16777216);   // yb1 and yb2
  __half* fvals  = (__half*)(ws + 16777216);
  bf16*   hmid_c = (bf16*) (ws + 16777216);
  float*  accum  = (float*)(ws + 33554432);
  bf16*   gvals  = (bf16*) (ws + 41943040);
  float*  outF   = (float*)d_out;

  dwconv_k<<<M_, 256, 0, stream>>>(x, cdw_w, cdw_b, dw_buf);
  gemm_bt<0><<<dim3(D_/128, M_/128), 256, 0, stream>>>(dw_buf, cpw_w, D_, cpw_b, x, yb, nullptr, nullptr, nullptr, M_, D_, D_);
  ln_k<<<M_, 256, 0, stream>>>(yb, ln1_g, ln1_b, xln);
  gemm_bt<1><<<dim3(E_/128, M_/128), 256, 0, stream>>>(xln, w_f, D_, nullptr, nullptr, nullptr, fvals, nullptr, nullptr, M_, E_, D_);
  gemm_bt<2><<<dim3(E_/128, M_/128), 256, 0, stream>>>(xln, w_i, D_, nullptr, nullptr, gvals, nullptr, nullptr, nullptr, M_, E_, D_);
  gemm_bt<3><<<dim3(E_/128, M_/128), 256, 0, stream>>>(xln, w_h, D_, nullptr, nullptr, gvals, nullptr, nullptr, nullptr, M_, E_, D_);
  scanA_k<<<(BE_*NCH)/256, 256, 0, stream>>>(fvals, gvals, Fc, Gc);
  scanB_k<<<BE_/256, 256, 0, stream>>>(Fc, Gc, hst);
  scanC_k<<<(BE_*NCH)/256, 256, 0, stream>>>(fvals, gvals, hst);
  gemm_bt<4><<<dim3(D_/128, M_/128), 256, 0, stream>>>(gvals, w_down, E_, nullptr, x, yb, nullptr, nullptr, nullptr, M_, D_, E_);
  ln_k<<<M_, 256, 0, stream>>>(yb, ln2_g, ln2_b, xln);
  // MLP in 4 chunks of 1024 over the hidden dim; fp32 accumulator for the 2nd GEMM
  for (int c = 0; c < 4; ++c) {
    gemm_bt<5><<<dim3(8, M_/128), 256, 0, stream>>>(xln, mlp_w1 + (size_t)c * 1024 * D_, D_,
                                                    mlp_b1 + c * 1024, nullptr,
                                                    hmid_c, nullptr, nullptr, nullptr, M_, 1024, D_);
    if (c == 0)
      gemm_bt<7><<<dim3(8, M_/128), 256, 0, stream>>>(hmid_c, mlp_w2 + c * 1024, 4 * D_,
                                                      mlp_b2, nullptr,
                                                      nullptr, nullptr, accum, nullptr, M_, D_, 1024);
    else if (c < 3)
      gemm_bt<8><<<dim3(8, M_/128), 256, 0, stream>>>(hmid_c, mlp_w2 + c * 1024, 4 * D_,
                                                      nullptr, nullptr,
                                                      nullptr, nullptr, accum, nullptr, M_, D_, 1024);
    else
      gemm_bt<9><<<dim3(8, M_/128), 256, 0, stream>>>(hmid_c, mlp_w2 + c * 1024, 4 * D_,
                                                      nullptr, nullptr,
                                                      nullptr, nullptr, accum, outF, M_, D_, 1024);
  }
}

// Round 6
// 773.576 us; speedup vs baseline: 1.5672x; 1.5672x over previous
//
#include <hip/hip_runtime.h>
#include <hip/hip_bf16.h>
#include <hip/hip_fp16.h>
#include <math.h>

using bf16 = __hip_bfloat16;
typedef __attribute__((ext_vector_type(8))) short s8v;   // 8 x bf16 raw (4 VGPRs)
typedef __attribute__((ext_vector_type(4))) float f32x4;

#define B_  4
#define S_  2048
#define D_  1024
#define E_  1536
#define M_  (B_*S_)     // 8192 tokens
#define BE_ (B_*E_)     // 6144 sequences
#define NCH 16          // scan chunks
#define CHS (S_/NCH)    // 128 steps per chunk

__device__ __forceinline__ float b2f(bf16 h) { return __bfloat162float(h); }
__device__ __forceinline__ bf16  f2b(float f) { return __float2bfloat16(f); }

struct __align__(8)  bh4 { bf16 h[4]; };

__device__ __forceinline__ void gld16(const void* g, void* l) {
  __builtin_amdgcn_global_load_lds((const __attribute__((address_space(1))) void*)g,
                                   (__attribute__((address_space(3))) void*)l, 16, 0, 0);
}

// ---------------- fp32 -> bf16 conversion ----------------
__global__ __launch_bounds__(256) void cvt_k(const float* __restrict__ s,
                                             bf16* __restrict__ d, int n)
{
  int i = (blockIdx.x * 256 + threadIdx.x) * 4;
  if (i < n) {
    float4 v = *(const float4*)(s + i);
    bh4 o;
    o.h[0] = f2b(v.x); o.h[1] = f2b(v.y); o.h[2] = f2b(v.z); o.h[3] = f2b(v.w);
    *(bh4*)(d + i) = o;
  }
}

// ---------------- depthwise causal conv (K=4), fp32 in -> bf16 out ----------------
__global__ __launch_bounds__(256) void dwconv_k(const float* __restrict__ x,
                                                const float* __restrict__ w,
                                                const float* __restrict__ bias,
                                                bf16* __restrict__ out)
{
  int m = blockIdx.x;          // b*S + s
  int s = m & (S_ - 1);
  int d = threadIdx.x * 4;
  float wf[4][4];
#pragma unroll
  for (int i = 0; i < 4; ++i) {
    float4 wr = *(const float4*)(w + (d + i) * 4);
    wf[i][0] = wr.x; wf[i][1] = wr.y; wf[i][2] = wr.z; wf[i][3] = wr.w;
  }
  float4 bb = *(const float4*)(bias + d);
  float acc[4] = {bb.x, bb.y, bb.z, bb.w};
#pragma unroll
  for (int k = 0; k < 4; ++k) {
    if (s - 3 + k >= 0) {
      float4 xv = *(const float4*)(x + (size_t)(m - 3 + k) * D_ + d);
      acc[0] += xv.x * wf[0][k];
      acc[1] += xv.y * wf[1][k];
      acc[2] += xv.z * wf[2][k];
      acc[3] += xv.w * wf[3][k];
    }
  }
  bh4 ov;
#pragma unroll
  for (int i = 0; i < 4; ++i) ov.h[i] = f2b(acc[i]);
  *(bh4*)(out + (size_t)m * D_ + d) = ov;
}

// ======== FAST PATH GEMM: C(M,N)=A(M,K,lda)*B^T(N,K,ldb), bf16+bf16, async staging ========
// m97 structure: global_load_lds width-16, 128x128 tile, BK=64, 4 waves 64x64.
// EPI: 0 outH=bf16(v+bias+resid_f32) | 1 dual raw store: col<1536->outH else outH2 (N=3072)
//      2 RMW outH=bf16(gh(v)*sigmoid(outH_raw)) | 3 outH=bf16(v+resid_f32)
//      4 outH=bf16(gelu(v+bias)) | 5 outF=v+bias | 6 RMW outF=v+outF
template<int EPI>
__global__ __launch_bounds__(256) void gemm_ab(const bf16* __restrict__ A, int lda,
                                               const bf16* __restrict__ Bb, int ldb,
                                               const float* __restrict__ bias,
                                               const float* __restrict__ resid,
                                               bf16* outH, bf16* outH2, float* outF,
                                               int M, int N, int K)
{
  __shared__ __align__(16) bf16 lsA[128 * 64];
  __shared__ __align__(16) bf16 lsB[128 * 64];
  const int tid  = threadIdx.x;
  const int lane = tid & 63;
  const int wave = tid >> 6;
  const int m0 = blockIdx.y * 128, n0 = blockIdx.x * 128;
  const int wm = (wave >> 1) * 64, wn = (wave & 1) * 64;
  const int r = lane & 15, q = lane >> 4;
  f32x4 acc[4][4] = {};

  for (int k0 = 0; k0 < K; k0 += 64) {
#pragma unroll
    for (int i = 0; i < 4; ++i) {
      int c = i * 256 + tid;          // 16B chunk 0..1023; per-wave contiguous dest
      int row = c >> 3, cc = c & 7;
      gld16(A  + (size_t)(m0 + row) * lda + k0 + cc * 8, (char*)lsA + c * 16);
      gld16(Bb + (size_t)(n0 + row) * ldb + k0 + cc * 8, (char*)lsB + c * 16);
    }
    __syncthreads();                  // drains vmcnt -> LDS valid
#pragma unroll
    for (int kk = 0; kk < 64; kk += 32) {
      s8v af[4], bfr[4];
#pragma unroll
      for (int t = 0; t < 4; ++t) {
        af[t]  = *(const s8v*)(lsA + (wm + t * 16 + r) * 64 + kk + q * 8);
        bfr[t] = *(const s8v*)(lsB + (wn + t * 16 + r) * 64 + kk + q * 8);
      }
#pragma unroll
      for (int mi = 0; mi < 4; ++mi)
#pragma unroll
        for (int ni = 0; ni < 4; ++ni)
          acc[mi][ni] = __builtin_amdgcn_mfma_f32_16x16x32_bf16(af[mi], bfr[ni], acc[mi][ni], 0, 0, 0);
    }
    __syncthreads();
  }

#pragma unroll
  for (int mi = 0; mi < 4; ++mi) {
#pragma unroll
    for (int j = 0; j < 4; ++j) {
      int row = m0 + wm + mi * 16 + q * 4 + j;
#pragma unroll
      for (int ni = 0; ni < 4; ++ni) {
        int col = n0 + wn + ni * 16 + r;
        size_t idx = (size_t)row * N + col;
        float v = acc[mi][ni][j];
        if constexpr (EPI == 0) {
          outH[idx] = f2b(v + bias[col] + resid[idx]);
        } else if constexpr (EPI == 1) {
          if (col < 1536) outH [(size_t)row * 1536 + col]        = f2b(v);
          else            outH2[(size_t)row * 1536 + col - 1536] = f2b(v);
        } else if constexpr (EPI == 2) {
          float gh = (v >= 0.f) ? (v + 0.5f) : (1.f / (1.f + expf(-v)));
          float iv = 1.f / (1.f + expf(-b2f(outH[idx])));
          outH[idx] = f2b(gh * iv);
        } else if constexpr (EPI == 3) {
          outH[idx] = f2b(v + resid[idx]);
        } else if constexpr (EPI == 4) {
          float u = v + bias[col];
          outH[idx] = f2b(0.5f * u * (1.f + erff(u * 0.70710678118f)));
        } else if constexpr (EPI == 5) {
          outF[idx] = v + bias[col];
        } else {
          outF[idx] = v + outF[idx];
        }
      }
    }
  }
}

// ======== FALLBACK GEMM (r5, proven): fp32 B staged+converted in-kernel ========
template<int EPI>
__global__ __launch_bounds__(256) void gemm_bt(const bf16* __restrict__ A,
                                               const float* __restrict__ Bw, int ldb,
                                               const float* __restrict__ bias,
                                               const float* __restrict__ resid,
                                               bf16* outH, __half* outP,
                                               float* outF, float* outF2,
                                               int M, int N, int K)
{
  __shared__ __align__(16) bf16 lsA[128 * 64];
  __shared__ __align__(16) bf16 lsB[128 * 64];
  const int tid  = threadIdx.x;
  const int lane = tid & 63;
  const int wave = tid >> 6;
  const int m0 = blockIdx.y * 128, n0 = blockIdx.x * 128;
  const int wm = (wave >> 1) * 64, wn = (wave & 1) * 64;
  const int r = lane & 15, q = lane >> 4;
  f32x4 acc[4][4] = {};

  for (int k0 = 0; k0 < K; k0 += 64) {
    int4 ra[4]; float4 rbf[8];
#pragma unroll
    for (int i = 0; i < 4; ++i) {
      int c = i * 256 + tid;
      ra[i] = *(const int4*)(A + (size_t)(m0 + (c >> 3)) * K + k0 + (c & 7) * 8);
    }
#pragma unroll
    for (int i = 0; i < 8; ++i) {
      int c2 = i * 256 + tid;
      rbf[i] = *(const float4*)(Bw + (size_t)(n0 + (c2 >> 4)) * ldb + k0 + (c2 & 15) * 4);
    }
    __syncthreads();
#pragma unroll
    for (int i = 0; i < 4; ++i) {
      int c = i * 256 + tid;
      *(int4*)((char*)lsA + c * 16) = ra[i];
    }
#pragma unroll
    for (int i = 0; i < 8; ++i) {
      int c2 = i * 256 + tid;
      bh4 o;
      o.h[0] = f2b(rbf[i].x); o.h[1] = f2b(rbf[i].y);
      o.h[2] = f2b(rbf[i].z); o.h[3] = f2b(rbf[i].w);
      *(bh4*)(lsB + (c2 >> 4) * 64 + (c2 & 15) * 4) = o;
    }
    __syncthreads();
#pragma unroll
    for (int kk = 0; kk < 64; kk += 32) {
      s8v af[4], bfr[4];
#pragma unroll
      for (int t = 0; t < 4; ++t) {
        af[t]  = *(const s8v*)(lsA + (wm + t * 16 + r) * 64 + kk + q * 8);
        bfr[t] = *(const s8v*)(lsB + (wn + t * 16 + r) * 64 + kk + q * 8);
      }
#pragma unroll
      for (int mi = 0; mi < 4; ++mi)
#pragma unroll
        for (int ni = 0; ni < 4; ++ni)
          acc[mi][ni] = __builtin_amdgcn_mfma_f32_16x16x32_bf16(af[mi], bfr[ni], acc[mi][ni], 0, 0, 0);
    }
  }

#pragma unroll
  for (int mi = 0; mi < 4; ++mi) {
#pragma unroll
    for (int j = 0; j < 4; ++j) {
      int row = m0 + wm + mi * 16 + q * 4 + j;
#pragma unroll
      for (int ni = 0; ni < 4; ++ni) {
        int col = n0 + wn + ni * 16 + r;
        size_t idx = (size_t)row * N + col;
        float v = acc[mi][ni][j];
        if constexpr (EPI == 0) {
          outH[idx] = f2b(v + bias[col] + resid[idx]);
        } else if constexpr (EPI == 1) {
          outP[idx] = __float2half(1.f / (1.f + expf(-v)));
        } else if constexpr (EPI == 2) {
          outH[idx] = f2b(1.f / (1.f + expf(-v)));
        } else if constexpr (EPI == 3) {
          float gh = (v >= 0.f) ? (v + 0.5f) : (1.f / (1.f + expf(-v)));
          outH[idx] = f2b(gh * b2f(outH[idx]));
        } else if constexpr (EPI == 4) {
          outH[idx] = f2b(v + resid[idx]);
        } else if constexpr (EPI == 5) {
          float u = v + bias[col];
          outH[idx] = f2b(0.5f * u * (1.f + erff(u * 0.70710678118f)));
        } else if constexpr (EPI == 7) {
          outF[idx] = v + bias[col];
        } else if constexpr (EPI == 8) {
          outF[idx] += v;
        } else {
          outF2[idx] = v + outF[idx];
        }
      }
    }
  }
}

// ---------------- LayerNorm over D=1024, bf16 in -> bf16 out ----------------
__global__ __launch_bounds__(256) void ln_k(const bf16* __restrict__ y,
                                            const float* __restrict__ g,
                                            const float* __restrict__ b,
                                            bf16* __restrict__ out)
{
  __shared__ float sm[8];
  int row = blockIdx.x;
  bh4 v4 = ((const bh4*)(y + (size_t)row * D_))[threadIdx.x];
  float v0 = b2f(v4.h[0]), v1 = b2f(v4.h[1]), v2 = b2f(v4.h[2]), v3 = b2f(v4.h[3]);
  float s = v0 + v1 + v2 + v3;
#pragma unroll
  for (int o = 32; o; o >>= 1) s += __shfl_down(s, o);
  int lane = threadIdx.x & 63, w = threadIdx.x >> 6;
  if (lane == 0) sm[w] = s;
  __syncthreads();
  float mu = (sm[0] + sm[1] + sm[2] + sm[3]) * (1.f / D_);
  float d0 = v0 - mu, d1 = v1 - mu, d2 = v2 - mu, d3 = v3 - mu;
  float qq = d0 * d0 + d1 * d1 + d2 * d2 + d3 * d3;
#pragma unroll
  for (int o = 32; o; o >>= 1) qq += __shfl_down(qq, o);
  if (lane == 0) sm[4 + w] = qq;
  __syncthreads();
  float var = (sm[4] + sm[5] + sm[6] + sm[7]) * (1.f / D_);
  float inv = rsqrtf(var + 1e-5f);
  int c = threadIdx.x * 4;
  float4 gv = *(const float4*)(g + c);
  float4 bv = *(const float4*)(b + c);
  bh4 ov;
  ov.h[0] = f2b(d0 * inv * gv.x + bv.x);
  ov.h[1] = f2b(d1 * inv * gv.y + bv.y);
  ov.h[2] = f2b(d2 * inv * gv.z + bv.z);
  ov.h[3] = f2b(d3 * inv * gv.w + bv.w);
  *(bh4*)(out + (size_t)row * D_ + c) = ov;
}

// ---------------- scans (fast path: raw bf16 f-pre + ready g) ----------------
__global__ __launch_bounds__(256) void scanA2_k(const bf16* __restrict__ fpre,
                                                const bf16* __restrict__ g,
                                                float* __restrict__ Fc, float* __restrict__ Gc)
{
  int gth = blockIdx.x * 256 + threadIdx.x;
  int c = gth / BE_, be = gth % BE_;
  int b = be / E_,  e = be % E_;
  size_t idx = (size_t)b * S_ * E_ + (size_t)c * CHS * E_ + e;
  float F = 1.f, G = 0.f;
  for (int sl = 0; sl < CHS; ++sl, idx += E_) {
    float fv = 1.f / (1.f + expf(-b2f(fpre[idx])));
    F *= fv;
    G = fv * G + b2f(g[idx]);
  }
  Fc[gth] = F; Gc[gth] = G;
}

__global__ __launch_bounds__(256) void scanB_k(const float* __restrict__ Fc,
                                               const float* __restrict__ Gc,
                                               float* __restrict__ hst)
{
  int be = blockIdx.x * 256 + threadIdx.x;
  float h = 0.5f;
#pragma unroll
  for (int c = 0; c < NCH; ++c) {
    hst[c * BE_ + be] = h;
    h = Fc[c * BE_ + be] * h + Gc[c * BE_ + be];
  }
}

__global__ __launch_bounds__(256) void scanC2_k(const bf16* __restrict__ fpre,
                                                bf16* g,
                                                const float* __restrict__ hst)
{
  int gth = blockIdx.x * 256 + threadIdx.x;
  int c = gth / BE_, be = gth % BE_;
  int b = be / E_,  e = be % E_;
  size_t idx = (size_t)b * S_ * E_ + (size_t)c * CHS * E_ + e;
  float h = hst[gth];
  for (int sl = 0; sl < CHS; ++sl, idx += E_) {
    float fv = 1.f / (1.f + expf(-b2f(fpre[idx])));
    h = fv * h + b2f(g[idx]);
    g[idx] = f2b(h);
  }
}

// ---------------- scans (fallback: fp16 f + ready g) ----------------
__global__ __launch_bounds__(256) void scanA_k(const __half* __restrict__ f,
                                               const bf16* __restrict__ g,
                                               float* __restrict__ Fc, float* __restrict__ Gc)
{
  int gth = blockIdx.x * 256 + threadIdx.x;
  int c = gth / BE_, be = gth % BE_;
  int b = be / E_,  e = be % E_;
  size_t idx = (size_t)b * S_ * E_ + (size_t)c * CHS * E_ + e;
  float F = 1.f, G = 0.f;
  for (int sl = 0; sl < CHS; ++sl, idx += E_) {
    float fv = __half2float(f[idx]);
    F *= fv;
    G = fv * G + b2f(g[idx]);
  }
  Fc[gth] = F; Gc[gth] = G;
}

__global__ __launch_bounds__(256) void scanC_k(const __half* __restrict__ f,
                                               bf16* g,
                                               const float* __restrict__ hst)
{
  int gth = blockIdx.x * 256 + threadIdx.x;
  int c = gth / BE_, be = gth % BE_;
  int b = be / E_,  e = be % E_;
  size_t idx = (size_t)b * S_ * E_ + (size_t)c * CHS * E_ + e;
  float h = hst[gth];
  for (int sl = 0; sl < CHS; ++sl, idx += E_) {
    float fv = __half2float(f[idx]);
    h = fv * h + b2f(g[idx]);
    g[idx] = f2b(h);
  }
}

extern "C" void kernel_launch(void* const* d_in, const int* in_sizes, int n_in,
                              void* d_out, int out_size, void* d_ws, size_t ws_size,
                              hipStream_t stream)
{
  (void)in_sizes; (void)n_in; (void)out_size;
  const float* x      = (const float*)d_in[0];
  const float* cdw_w  = (const float*)d_in[1];
  const float* cdw_b  = (const float*)d_in[2];
  const float* cpw_w  = (const float*)d_in[3];
  const float* cpw_b  = (const float*)d_in[4];
  const float* ln1_g  = (const float*)d_in[5];
  const float* ln1_b  = (const float*)d_in[6];
  const float* w_f    = (const float*)d_in[7];
  const float* w_i    = (const float*)d_in[8];
  const float* w_h    = (const float*)d_in[9];
  const float* w_down = (const float*)d_in[10];
  const float* ln2_g  = (const float*)d_in[11];
  const float* ln2_b  = (const float*)d_in[12];
  const float* mlp_w1 = (const float*)d_in[13];
  const float* mlp_b1 = (const float*)d_in[14];
  const float* mlp_w2 = (const float*)d_in[15];
  const float* mlp_b2 = (const float*)d_in[16];
  char* ws = (char*)d_ws;
  float* outF = (float*)d_out;

  if (ws_size >= (size_t)112 * 1024 * 1024) {
    // ===== FAST PATH (110 MiB) =====
    // [0,16M)   dw_buf(k1-2) / xln(k3-5, k10-11); Fc/Gc/hst @[0,1.2M) during scans
    // [16,32M)  yb (k2-3, k9-10)
    // [32,56M)  fpre raw bf16 (k4..k8)        ; hmid_c 32M @[32,64M) k11+ (gates dead)
    // [56,80M)  ipre raw -> g=gh*sig(i) RMW (k5) -> h in-place (k8) -> down A (k9)
    // [80,110M) bf16 weights: pw@80 wfi@82 wh@88 wd@91 w1@94 w2@102
    bf16* dw_buf = (bf16*)(ws + 0);
    bf16* xln    = (bf16*)(ws + 0);
    float* Fc    = (float*)(ws + 0);
    float* Gc    = (float*)(ws + 393216);
    float* hst   = (float*)(ws + 786432);
    bf16* yb     = (bf16*)(ws + 16777216);
    bf16* fpre   = (bf16*)(ws + 33554432);
    bf16* hmid_c = (bf16*)(ws + 33554432);
    bf16* gvals  = (bf16*)(ws + 58720256);
    bf16* pwb    = (bf16*)(ws + 83886080);
    bf16* wfib   = (bf16*)(ws + 85983232);
    bf16* whb    = (bf16*)(ws + 92274688);
    bf16* wdb    = (bf16*)(ws + 95420416);
    bf16* w1b    = (bf16*)(ws + 98566144);
    bf16* w2b    = (bf16*)(ws + 106954752);

    cvt_k<<<(D_*D_)/1024,   256, 0, stream>>>(cpw_w,  pwb, D_*D_);
    cvt_k<<<(E_*D_)/1024,   256, 0, stream>>>(w_f,    wfib, E_*D_);
    cvt_k<<<(E_*D_)/1024,   256, 0, stream>>>(w_i,    wfib + E_*D_, E_*D_);
    cvt_k<<<(E_*D_)/1024,   256, 0, stream>>>(w_h,    whb, E_*D_);
    cvt_k<<<(D_*E_)/1024,   256, 0, stream>>>(w_down, wdb, D_*E_);
    cvt_k<<<(4*D_*D_)/1024, 256, 0, stream>>>(mlp_w1, w1b, 4*D_*D_);
    cvt_k<<<(4*D_*D_)/1024, 256, 0, stream>>>(mlp_w2, w2b, 4*D_*D_);

    dwconv_k<<<M_, 256, 0, stream>>>(x, cdw_w, cdw_b, dw_buf);
    gemm_ab<0><<<dim3(8, 64), 256, 0, stream>>>(dw_buf, D_, pwb, D_, cpw_b, x, yb, nullptr, nullptr, M_, D_, D_);
    ln_k<<<M_, 256, 0, stream>>>(yb, ln1_g, ln1_b, xln);
    // fused f+i raw pre-activations (N=3072), then h RMW: g = gh(v)*sigmoid(ipre)
    gemm_ab<1><<<dim3(24, 64), 256, 0, stream>>>(xln, D_, wfib, D_, nullptr, nullptr, fpre, gvals, nullptr, M_, 3072, D_);
    gemm_ab<2><<<dim3(12, 64), 256, 0, stream>>>(xln, D_, whb, D_, nullptr, nullptr, gvals, nullptr, nullptr, M_, E_, D_);
    scanA2_k<<<(BE_*NCH)/256, 256, 0, stream>>>(fpre, gvals, Fc, Gc);
    scanB_k<<<BE_/256, 256, 0, stream>>>(Fc, Gc, hst);
    scanC2_k<<<(BE_*NCH)/256, 256, 0, stream>>>(fpre, gvals, hst);
    gemm_ab<3><<<dim3(8, 64), 256, 0, stream>>>(gvals, E_, wdb, E_, nullptr, x, yb, nullptr, nullptr, M_, D_, E_);
    ln_k<<<M_, 256, 0, stream>>>(yb, ln2_g, ln2_b, xln);
    // MLP in 2 chunks of 2048; d_out (fp32) is the accumulator
    for (int c = 0; c < 2; ++c) {
      gemm_ab<4><<<dim3(16, 64), 256, 0, stream>>>(xln, D_, w1b + (size_t)c * 2048 * D_, D_,
                                                   mlp_b1 + c * 2048, nullptr,
                                                   hmid_c, nullptr, nullptr, M_, 2048, D_);
      if (c == 0)
        gemm_ab<5><<<dim3(8, 64), 256, 0, stream>>>(hmid_c, 2048, w2b + 0, 4 * D_,
                                                    mlp_b2, nullptr, nullptr, nullptr, outF, M_, D_, 2048);
      else
        gemm_ab<6><<<dim3(8, 64), 256, 0, stream>>>(hmid_c, 2048, w2b + 2048, 4 * D_,
                                                    nullptr, nullptr, nullptr, nullptr, outF, M_, D_, 2048);
    }
  } else {
    // ===== FALLBACK: r5 proven path (64 MiB) =====
    bf16*   dw_buf = (bf16*) (ws + 0);
    bf16*   xln    = (bf16*) (ws + 0);
    float*  Fc     = (float*)(ws + 0);
    float*  Gc     = (float*)(ws + 393216);
    float*  hst    = (float*)(ws + 786432);
    bf16*   yb     = (bf16*) (ws + 16777216);
    __half* fvals  = (__half*)(ws + 16777216);
    bf16*   hmid_c = (bf16*) (ws + 16777216);
    float*  accum  = (float*)(ws + 33554432);
    bf16*   gvals  = (bf16*) (ws + 41943040);

    dwconv_k<<<M_, 256, 0, stream>>>(x, cdw_w, cdw_b, dw_buf);
    gemm_bt<0><<<dim3(D_/128, M_/128), 256, 0, stream>>>(dw_buf, cpw_w, D_, cpw_b, x, yb, nullptr, nullptr, nullptr, M_, D_, D_);
    ln_k<<<M_, 256, 0, stream>>>(yb, ln1_g, ln1_b, xln);
    gemm_bt<1><<<dim3(E_/128, M_/128), 256, 0, stream>>>(xln, w_f, D_, nullptr, nullptr, nullptr, fvals, nullptr, nullptr, M_, E_, D_);
    gemm_bt<2><<<dim3(E_/128, M_/128), 256, 0, stream>>>(xln, w_i, D_, nullptr, nullptr, gvals, nullptr, nullptr, nullptr, M_, E_, D_);
    gemm_bt<3><<<dim3(E_/128, M_/128), 256, 0, stream>>>(xln, w_h, D_, nullptr, nullptr, gvals, nullptr, nullptr, nullptr, M_, E_, D_);
    scanA_k<<<(BE_*NCH)/256, 256, 0, stream>>>(fvals, gvals, Fc, Gc);
    scanB_k<<<BE_/256, 256, 0, stream>>>(Fc, Gc, hst);
    scanC_k<<<(BE_*NCH)/256, 256, 0, stream>>>(fvals, gvals, hst);
    gemm_bt<4><<<dim3(D_/128, M_/128), 256, 0, stream>>>(gvals, w_down, E_, nullptr, x, yb, nullptr, nullptr, nullptr, M_, D_, E_);
    ln_k<<<M_, 256, 0, stream>>>(yb, ln2_g, ln2_b, xln);
    for (int c = 0; c < 4; ++c) {
      gemm_bt<5><<<dim3(8, M_/128), 256, 0, stream>>>(xln, mlp_w1 + (size_t)c * 1024 * D_, D_,
                                                      mlp_b1 + c * 1024, nullptr,
                                                      hmid_c, nullptr, nullptr, nullptr, M_, 1024, D_);
      if (c == 0)
        gemm_bt<7><<<dim3(8, M_/128), 256, 0, stream>>>(hmid_c, mlp_w2 + c * 1024, 4 * D_,
                                                        mlp_b2, nullptr, nullptr, nullptr, accum, nullptr, M_, D_, 1024);
      else if (c < 3)
        gemm_bt<8><<<dim3(8, M_/128), 256, 0, stream>>>(hmid_c, mlp_w2 + c * 1024, 4 * D_,
                                                        nullptr, nullptr, nullptr, nullptr, accum, nullptr, M_, D_, 1024);
      else
        gemm_bt<9><<<dim3(8, M_/128), 256, 0, stream>>>(hmid_c, mlp_w2 + c * 1024, 4 * D_,
                                                        nullptr, nullptr, nullptr, nullptr, accum, outF, M_, D_, 1024);
    }
  }
}

// Round 7
// 673.170 us; speedup vs baseline: 1.8009x; 1.1492x over previous
//
#include <hip/hip_runtime.h>
#include <hip/hip_bf16.h>
#include <math.h>

using bf16 = __hip_bfloat16;
typedef __attribute__((ext_vector_type(8))) short s8v;   // 8 x bf16 raw (4 VGPRs)
typedef __attribute__((ext_vector_type(4))) float f32x4;

#define B_  4
#define S_  2048
#define D_  1024
#define E_  1536
#define M_  (B_*S_)     // 8192 tokens
#define BE_ (B_*E_)     // 6144 sequences
#define NCH 16          // scan chunks
#define CHS (S_/NCH)    // 128 steps per chunk

__device__ __forceinline__ float b2f(bf16 h) { return __bfloat162float(h); }
__device__ __forceinline__ bf16  f2b(float f) { return __float2bfloat16(f); }

struct __align__(8)  bh4 { bf16 h[4]; };

__device__ __forceinline__ void gld16(const void* g, void* l) {
  __builtin_amdgcn_global_load_lds((const __attribute__((address_space(1))) void*)g,
                                   (__attribute__((address_space(3))) void*)l, 16, 0, 0);
}

// ---------------- fp32 -> bf16 conversion ----------------
__global__ __launch_bounds__(256) void cvt_k(const float* __restrict__ s,
                                             bf16* __restrict__ d, int n)
{
  int i = (blockIdx.x * 256 + threadIdx.x) * 4;
  if (i < n) {
    float4 v = *(const float4*)(s + i);
    bh4 o;
    o.h[0] = f2b(v.x); o.h[1] = f2b(v.y); o.h[2] = f2b(v.z); o.h[3] = f2b(v.w);
    *(bh4*)(d + i) = o;
  }
}

// ---------------- depthwise causal conv (K=4), fp32 in -> bf16 out ----------------
__global__ __launch_bounds__(256) void dwconv_k(const float* __restrict__ x,
                                                const float* __restrict__ w,
                                                const float* __restrict__ bias,
                                                bf16* __restrict__ out)
{
  int m = blockIdx.x;          // b*S + s
  int s = m & (S_ - 1);
  int d = threadIdx.x * 4;
  float wf[4][4];
#pragma unroll
  for (int i = 0; i < 4; ++i) {
    float4 wr = *(const float4*)(w + (d + i) * 4);
    wf[i][0] = wr.x; wf[i][1] = wr.y; wf[i][2] = wr.z; wf[i][3] = wr.w;
  }
  float4 bb = *(const float4*)(bias + d);
  float acc[4] = {bb.x, bb.y, bb.z, bb.w};
#pragma unroll
  for (int k = 0; k < 4; ++k) {
    if (s - 3 + k >= 0) {
      float4 xv = *(const float4*)(x + (size_t)(m - 3 + k) * D_ + d);
      acc[0] += xv.x * wf[0][k];
      acc[1] += xv.y * wf[1][k];
      acc[2] += xv.z * wf[2][k];
      acc[3] += xv.w * wf[3][k];
    }
  }
  bh4 ov;
#pragma unroll
  for (int i = 0; i < 4; ++i) ov.h[i] = f2b(acc[i]);
  *(bh4*)(out + (size_t)m * D_ + d) = ov;
}

// ======== GEMM: C(M,N)=A(M,K,lda)*B^T(N,K,ldb), bf16, async staging, XOR-swizzled LDS ========
// LDS tile 128x64 bf16 stored as 8x16B chunks/row; chunk slot s of row holds global
// column-group (s ^ (row&7)) -> fragment reads hit all 8 bank-groups (2-way max).
// EPI: 0 outH=bf16(v+bias+resid_f32) | 1 dual raw store col<1536->outH else outH2 (N=3072)
//      2 RMW outH=bf16(gh(v)*sigmoid(outH_raw)) | 3 outH=bf16(v+resid_f32)
//      4 outH=bf16(gelu(v+bias)) | 5 outF=v+bias (fp32 final)
template<int EPI>
__global__ __launch_bounds__(256) void gemm_ab(const bf16* __restrict__ A, int lda,
                                               const bf16* __restrict__ Bb, int ldb,
                                               const float* __restrict__ bias,
                                               const float* __restrict__ resid,
                                               bf16* outH, bf16* outH2, float* outF,
                                               int M, int N, int K)
{
  __shared__ __align__(16) bf16 lsA[128 * 64];
  __shared__ __align__(16) bf16 lsB[128 * 64];
  const int tid  = threadIdx.x;
  const int lane = tid & 63;
  const int wave = tid >> 6;
  const int m0 = blockIdx.y * 128, n0 = blockIdx.x * 128;
  const int wm = (wave >> 1) * 64, wn = (wave & 1) * 64;
  const int r = lane & 15, q = lane >> 4;
  const int sw = r & 7;
  f32x4 acc[4][4] = {};

  for (int k0 = 0; k0 < K; k0 += 64) {
#pragma unroll
    for (int i = 0; i < 4; ++i) {
      int c = i * 256 + tid;                   // LDS chunk id 0..1023 (dest = c*16, per-wave contiguous)
      int row = c >> 3, cc = (c & 7) ^ (row & 7);  // swizzled global column-group
      gld16(A  + (size_t)(m0 + row) * lda + k0 + cc * 8, (char*)lsA + c * 16);
      gld16(Bb + (size_t)(n0 + row) * ldb + k0 + cc * 8, (char*)lsB + c * 16);
    }
    __syncthreads();                  // drains vmcnt -> LDS valid
#pragma unroll
    for (int kk = 0; kk < 64; kk += 32) {
      const int j = (kk >> 3) + q;    // global 16B column-group 0..7
      s8v af[4], bfr[4];
#pragma unroll
      for (int t = 0; t < 4; ++t) {
        af[t]  = *(const s8v*)((char*)lsA + (((wm + t * 16 + r) << 3) + (j ^ sw)) * 16);
        bfr[t] = *(const s8v*)((char*)lsB + (((wn + t * 16 + r) << 3) + (j ^ sw)) * 16);
      }
#pragma unroll
      for (int mi = 0; mi < 4; ++mi)
#pragma unroll
        for (int ni = 0; ni < 4; ++ni)
          acc[mi][ni] = __builtin_amdgcn_mfma_f32_16x16x32_bf16(af[mi], bfr[ni], acc[mi][ni], 0, 0, 0);
    }
    __syncthreads();
  }

#pragma unroll
  for (int mi = 0; mi < 4; ++mi) {
#pragma unroll
    for (int j = 0; j < 4; ++j) {
      int row = m0 + wm + mi * 16 + q * 4 + j;
#pragma unroll
      for (int ni = 0; ni < 4; ++ni) {
        int col = n0 + wn + ni * 16 + r;
        size_t idx = (size_t)row * N + col;
        float v = acc[mi][ni][j];
        if constexpr (EPI == 0) {
          outH[idx] = f2b(v + bias[col] + resid[idx]);
        } else if constexpr (EPI == 1) {
          if (col < 1536) outH [(size_t)row * 1536 + col]        = f2b(v);
          else            outH2[(size_t)row * 1536 + col - 1536] = f2b(v);
        } else if constexpr (EPI == 2) {
          float gh = (v >= 0.f) ? (v + 0.5f) : (1.f / (1.f + expf(-v)));
          float iv = 1.f / (1.f + expf(-b2f(outH[idx])));
          outH[idx] = f2b(gh * iv);
        } else if constexpr (EPI == 3) {
          outH[idx] = f2b(v + resid[idx]);
        } else if constexpr (EPI == 4) {
          float u = v + bias[col];
          outH[idx] = f2b(0.5f * u * (1.f + erff(u * 0.70710678118f)));
        } else {
          outF[idx] = v + bias[col];
        }
      }
    }
  }
}

// ---------------- LayerNorm over D=1024, bf16 in -> bf16 out ----------------
__global__ __launch_bounds__(256) void ln_k(const bf16* __restrict__ y,
                                            const float* __restrict__ g,
                                            const float* __restrict__ b,
                                            bf16* __restrict__ out)
{
  __shared__ float sm[8];
  int row = blockIdx.x;
  bh4 v4 = ((const bh4*)(y + (size_t)row * D_))[threadIdx.x];
  float v0 = b2f(v4.h[0]), v1 = b2f(v4.h[1]), v2 = b2f(v4.h[2]), v3 = b2f(v4.h[3]);
  float s = v0 + v1 + v2 + v3;
#pragma unroll
  for (int o = 32; o; o >>= 1) s += __shfl_down(s, o);
  int lane = threadIdx.x & 63, w = threadIdx.x >> 6;
  if (lane == 0) sm[w] = s;
  __syncthreads();
  float mu = (sm[0] + sm[1] + sm[2] + sm[3]) * (1.f / D_);
  float d0 = v0 - mu, d1 = v1 - mu, d2 = v2 - mu, d3 = v3 - mu;
  float qq = d0 * d0 + d1 * d1 + d2 * d2 + d3 * d3;
#pragma unroll
  for (int o = 32; o; o >>= 1) qq += __shfl_down(qq, o);
  if (lane == 0) sm[4 + w] = qq;
  __syncthreads();
  float var = (sm[4] + sm[5] + sm[6] + sm[7]) * (1.f / D_);
  float inv = rsqrtf(var + 1e-5f);
  int c = threadIdx.x * 4;
  float4 gv = *(const float4*)(g + c);
  float4 bv = *(const float4*)(b + c);
  bh4 ov;
  ov.h[0] = f2b(d0 * inv * gv.x + bv.x);
  ov.h[1] = f2b(d1 * inv * gv.y + bv.y);
  ov.h[2] = f2b(d2 * inv * gv.z + bv.z);
  ov.h[3] = f2b(d3 * inv * gv.w + bv.w);
  *(bh4*)(out + (size_t)row * D_ + c) = ov;
}

// ---------------- chunked linear-recurrence scan: h' = sigmoid(fpre)*h + g ----------------
__global__ __launch_bounds__(256) void scanA2_k(const bf16* __restrict__ fpre,
                                                const bf16* __restrict__ g,
                                                float* __restrict__ Fc, float* __restrict__ Gc)
{
  int gth = blockIdx.x * 256 + threadIdx.x;
  int c = gth / BE_, be = gth % BE_;
  int b = be / E_,  e = be % E_;
  size_t idx = (size_t)b * S_ * E_ + (size_t)c * CHS * E_ + e;
  float F = 1.f, G = 0.f;
  for (int sl = 0; sl < CHS; ++sl, idx += E_) {
    float fv = 1.f / (1.f + expf(-b2f(fpre[idx])));
    F *= fv;
    G = fv * G + b2f(g[idx]);
  }
  Fc[gth] = F; Gc[gth] = G;
}

__global__ __launch_bounds__(256) void scanB_k(const float* __restrict__ Fc,
                                               const float* __restrict__ Gc,
                                               float* __restrict__ hst)
{
  int be = blockIdx.x * 256 + threadIdx.x;
  float h = 0.5f;
#pragma unroll
  for (int c = 0; c < NCH; ++c) {
    hst[c * BE_ + be] = h;
    h = Fc[c * BE_ + be] * h + Gc[c * BE_ + be];
  }
}

__global__ __launch_bounds__(256) void scanC2_k(const bf16* __restrict__ fpre,
                                                bf16* g,
                                                const float* __restrict__ hst)
{
  int gth = blockIdx.x * 256 + threadIdx.x;
  int c = gth / BE_, be = gth % BE_;
  int b = be / E_,  e = be % E_;
  size_t idx = (size_t)b * S_ * E_ + (size_t)c * CHS * E_ + e;
  float h = hst[gth];
  for (int sl = 0; sl < CHS; ++sl, idx += E_) {
    float fv = 1.f / (1.f + expf(-b2f(fpre[idx])));
    h = fv * h + b2f(g[idx]);
    g[idx] = f2b(h);
  }
}

extern "C" void kernel_launch(void* const* d_in, const int* in_sizes, int n_in,
                              void* d_out, int out_size, void* d_ws, size_t ws_size,
                              hipStream_t stream)
{
  (void)in_sizes; (void)n_in; (void)out_size; (void)ws_size;
  const float* x      = (const float*)d_in[0];
  const float* cdw_w  = (const float*)d_in[1];
  const float* cdw_b  = (const float*)d_in[2];
  const float* cpw_w  = (const float*)d_in[3];
  const float* cpw_b  = (const float*)d_in[4];
  const float* ln1_g  = (const float*)d_in[5];
  const float* ln1_b  = (const float*)d_in[6];
  const float* w_f    = (const float*)d_in[7];
  const float* w_i    = (const float*)d_in[8];
  const float* w_h    = (const float*)d_in[9];
  const float* w_down = (const float*)d_in[10];
  const float* ln2_g  = (const float*)d_in[11];
  const float* ln2_b  = (const float*)d_in[12];
  const float* mlp_w1 = (const float*)d_in[13];
  const float* mlp_b1 = (const float*)d_in[14];
  const float* mlp_w2 = (const float*)d_in[15];
  const float* mlp_b2 = (const float*)d_in[16];
  char* ws = (char*)d_ws;
  float* outF = (float*)d_out;

  // 110 MiB workspace (ws_size >= 112 MiB verified by r6 fast path running).
  // [0,16M)   dw_buf(k1-2) / xln(k3-6, k10-11); Fc/Gc/hst @[0,1.2M) during scans (xln dead)
  // [16,32M)  yb (k2-3, k9-10)
  // [16,80M)  hmid (k11a-b) — over yb/fpre/gvals, all dead after ln2/down
  // [32,58M)  fpre raw bf16 (k4..k8c)
  // [58,80M)  ipre raw -> g=gh*sig(i) RMW (k6) -> h in-place (k8c) -> down A (k9)
  // [80,110M) bf16 weights: pw | wfi | wh | wd | w1 | w2
  bf16* dw_buf = (bf16*)(ws + 0);
  bf16* xln    = (bf16*)(ws + 0);
  float* Fc    = (float*)(ws + 0);
  float* Gc    = (float*)(ws + 393216);
  float* hst   = (float*)(ws + 786432);
  bf16* yb     = (bf16*)(ws + 16777216);
  bf16* hmid   = (bf16*)(ws + 16777216);   // 8192x4096 bf16 = 64 MiB, ends at 80 MiB
  bf16* fpre   = (bf16*)(ws + 33554432);
  bf16* gvals  = (bf16*)(ws + 58720256);
  bf16* pwb    = (bf16*)(ws + 83886080);
  bf16* wfib   = (bf16*)(ws + 85983232);
  bf16* whb    = (bf16*)(ws + 92274688);
  bf16* wdb    = (bf16*)(ws + 95420416);
  bf16* w1b    = (bf16*)(ws + 98566144);
  bf16* w2b    = (bf16*)(ws + 106954752);

  cvt_k<<<(D_*D_)/1024,   256, 0, stream>>>(cpw_w,  pwb, D_*D_);
  cvt_k<<<(E_*D_)/1024,   256, 0, stream>>>(w_f,    wfib, E_*D_);
  cvt_k<<<(E_*D_)/1024,   256, 0, stream>>>(w_i,    wfib + E_*D_, E_*D_);
  cvt_k<<<(E_*D_)/1024,   256, 0, stream>>>(w_h,    whb, E_*D_);
  cvt_k<<<(D_*E_)/1024,   256, 0, stream>>>(w_down, wdb, D_*E_);
  cvt_k<<<(4*D_*D_)/1024, 256, 0, stream>>>(mlp_w1, w1b, 4*D_*D_);
  cvt_k<<<(4*D_*D_)/1024, 256, 0, stream>>>(mlp_w2, w2b, 4*D_*D_);

  dwconv_k<<<M_, 256, 0, stream>>>(x, cdw_w, cdw_b, dw_buf);
  gemm_ab<0><<<dim3(8, 64), 256, 0, stream>>>(dw_buf, D_, pwb, D_, cpw_b, x, yb, nullptr, nullptr, M_, D_, D_);
  ln_k<<<M_, 256, 0, stream>>>(yb, ln1_g, ln1_b, xln);
  // fused f+i raw pre-activations (N=3072), then h RMW: g = gh(v)*sigmoid(ipre)
  gemm_ab<1><<<dim3(24, 64), 256, 0, stream>>>(xln, D_, wfib, D_, nullptr, nullptr, fpre, gvals, nullptr, M_, 3072, D_);
  gemm_ab<2><<<dim3(12, 64), 256, 0, stream>>>(xln, D_, whb, D_, nullptr, nullptr, gvals, nullptr, nullptr, M_, E_, D_);
  scanA2_k<<<(BE_*NCH)/256, 256, 0, stream>>>(fpre, gvals, Fc, Gc);
  scanB_k<<<BE_/256, 256, 0, stream>>>(Fc, Gc, hst);
  scanC2_k<<<(BE_*NCH)/256, 256, 0, stream>>>(fpre, gvals, hst);
  gemm_ab<3><<<dim3(8, 64), 256, 0, stream>>>(gvals, E_, wdb, E_, nullptr, x, yb, nullptr, nullptr, M_, D_, E_);
  ln_k<<<M_, 256, 0, stream>>>(yb, ln2_g, ln2_b, xln);
  // fused MLP: one N=4096 GEMM -> hmid, one K=4096 GEMM -> d_out (fp32, single write)
  gemm_ab<4><<<dim3(32, 64), 256, 0, stream>>>(xln, D_, w1b, D_, mlp_b1, nullptr, hmid, nullptr, nullptr, M_, 4*D_, D_);
  gemm_ab<5><<<dim3(8, 64), 256, 0, stream>>>(hmid, 4*D_, w2b, 4*D_, mlp_b2, nullptr, nullptr, nullptr, outF, M_, D_, 4*D_);
}